// Round 3
// baseline (693.313 us; speedup 1.0000x reference)
//
#include <hip/hip_runtime.h>
#include <stdint.h>

#define N_NODES 100000
#define NPAD    100032
#define DIM 128
#define NNZ_E 1600000
#define SCAN_TILE 2048
#define N_TILES ((N_NODES + SCAN_TILE - 1) / SCAN_TILE)   // 49

typedef float f32x4  __attribute__((ext_vector_type(4)));
typedef short bf16x8 __attribute__((ext_vector_type(8)));

union B8 { uint4 q; unsigned u[4]; bf16x8 v; };

__device__ __forceinline__ unsigned short f2bs(float f) {   // fp32 -> bf16 RNE
    unsigned u = __builtin_bit_cast(unsigned, f);
    u = (u + 0x7fffu + ((u >> 16) & 1u)) >> 16;
    return (unsigned short)u;
}
// HW packed fp32->bf16 RNE convert: 1 instruction replaces ~8
__device__ __forceinline__ unsigned cvtpk(float lo, float hi) {
    unsigned r;
    asm("v_cvt_pk_bf16_f32 %0, %1, %2" : "=v"(r) : "v"(lo), "v"(hi));
    return r;
}
#define UNPK(u32, flo, fhi) { flo = __builtin_bit_cast(float, (unsigned)((u32) << 16)); \
                              fhi = __builtin_bit_cast(float, (unsigned)((u32) & 0xffff0000u)); }

// ---------------------------------------------------------------------------
// emb -> out[:,0:128] fp32  AND  xA bf16 (pad rows zeroed here: no memset)
// ---------------------------------------------------------------------------
__global__ __launch_bounds__(256) void copy_emb_kernel(
    const float* __restrict__ emb, float* __restrict__ out,
    unsigned* __restrict__ xbuf)
{
    int tid = blockIdx.x * 256 + threadIdx.x;   // NPAD*32 threads, one float4 each
    int n = tid >> 5, c = tid & 31;
    if (n < N_NODES) {
        float4 v = ((const float4*)emb)[tid];
        *((float4*)(out + (size_t)n * 384) + c) = v;
        ((uint2*)xbuf)[(size_t)n * 32 + c] = make_uint2(cvtpk(v.x, v.y), cvtpk(v.z, v.w));
    } else {
        ((uint2*)xbuf)[(size_t)n * 32 + c] = make_uint2(0u, 0u);
    }
}

// ---------------------------------------------------------------------------
// Fused prep: W fp32 -> bf16 (both layers, both matrices) + zero cnt.
// ---------------------------------------------------------------------------
__global__ __launch_bounds__(256) void prep_kernel(
    const float* __restrict__ W1, const float* __restrict__ W2,
    unsigned* __restrict__ w1b, unsigned* __restrict__ w2b,
    int* __restrict__ cnt)
{
    int tid = blockIdx.x * 256 + threadIdx.x;
    if (tid < 8192) {
        float4 a = ((const float4*)W1)[tid];
        float4 b = ((const float4*)W2)[tid];
        ((uint2*)w1b)[tid] = make_uint2(cvtpk(a.x, a.y), cvtpk(a.z, a.w));
        ((uint2*)w2b)[tid] = make_uint2(cvtpk(b.x, b.y), cvtpk(b.z, b.w));
    }
    if (tid < 25000) ((uint4*)cnt)[tid] = make_uint4(0u, 0u, 0u, 0u);  // 100000 ints
}

// ---------------------------------------------------------------------------
// CSR build: histogram -> scan -> countdown scatter
// ---------------------------------------------------------------------------
__global__ __launch_bounds__(256) void hist_kernel(
    const int* __restrict__ rows, int* __restrict__ cnt)
{
    int e = blockIdx.x * 256 + threadIdx.x;
    atomicAdd(&cnt[rows[e]], 1);
}

__global__ __launch_bounds__(256) void scan_pass_a(
    const int* __restrict__ cnt, int* __restrict__ tile_sums)
{
    __shared__ int sdata[256];
    int base = blockIdx.x * SCAN_TILE + threadIdx.x * 8;
    int s = 0;
    #pragma unroll
    for (int q = 0; q < 8; ++q) {
        int i = base + q;
        s += (i < N_NODES) ? cnt[i] : 0;
    }
    sdata[threadIdx.x] = s;
    __syncthreads();
    for (int off = 128; off >= 1; off >>= 1) {
        if (threadIdx.x < off) sdata[threadIdx.x] += sdata[threadIdx.x + off];
        __syncthreads();
    }
    if (threadIdx.x == 0) tile_sums[blockIdx.x] = sdata[0];
}

// wave-parallel exclusive scan over 49 tile sums
__global__ void scan_pass_b(int* __restrict__ tile_sums)
{
    int lane = threadIdx.x;          // 64 lanes
    int v = (lane < N_TILES) ? tile_sums[lane] : 0;
    #pragma unroll
    for (int off = 1; off < 64; off <<= 1) {
        int u = __shfl_up(v, off);
        if (lane >= off) v += u;
    }
    int ex = __shfl_up(v, 1);
    if (lane == 0) ex = 0;
    if (lane < N_TILES) tile_sums[lane] = ex;
}

__global__ __launch_bounds__(256) void scan_pass_c(
    const int* __restrict__ cnt, const int* __restrict__ tile_offs,
    int* __restrict__ row_ptr)
{
    __shared__ int spart[256];
    int t = threadIdx.x;
    int base = blockIdx.x * SCAN_TILE + t * 8;
    int loc[8];
    int s = 0;
    #pragma unroll
    for (int q = 0; q < 8; ++q) {
        int i = base + q;
        int c = (i < N_NODES) ? cnt[i] : 0;
        loc[q] = s; s += c;
    }
    spart[t] = s;
    __syncthreads();
    for (int off = 1; off < 256; off <<= 1) {
        int v = (t >= off) ? spart[t - off] : 0;
        __syncthreads();
        spart[t] += v;
        __syncthreads();
    }
    int exoff = tile_offs[blockIdx.x] + spart[t] - s;
    #pragma unroll
    for (int q = 0; q < 8; ++q) {
        int i = base + q;
        if (i <= N_NODES) row_ptr[i] = exoff + loc[q];
    }
}

// scatter via countdown on cnt (scan passes only READ cnt) -> no second memset
__global__ __launch_bounds__(256) void scatter_kernel(
    const int* __restrict__ rows, const int* __restrict__ cols,
    const float* __restrict__ vals, const int* __restrict__ row_ptr,
    int* __restrict__ cnt, int2* __restrict__ edges)
{
    int e = blockIdx.x * 256 + threadIdx.x;
    int r = rows[e];
    int pos = row_ptr[r] + atomicSub(&cnt[r], 1) - 1;
    edges[pos] = make_int2(cols[e], __float_as_int(vals[e]));
}

// ---------------------------------------------------------------------------
// FUSED layer: SpMM gather + (side+x)@W1^T + (side*x)@W2^T + bias + leaky_relu
// + row L2-norm + out write (+ optional new-x write to xout).
//
// Block = 256 threads = 4 waves, 64 nodes.
// Phase 1 (gather): 16 groups of 16 lanes; group G owns nodes G*4..G*4+3.
//   Per node: lane l gathers uint4 (8 bf16 cols l*8..l*8+7) per edge; edge
//   descriptors loaded coalesced (16 int2/group) and broadcast via shfl-16.
//   fp32 side accum feeds a1=(s+x), a2=(s*x) bf16 frags directly into LDS
//   (XOR slot swizzle: both ds_write_b128 and ds_read_b128 conflict-free).
// Phase 2 (MFMA): wave w owns cols [w*32,+32); W frags in registers.
// sideb buffer is GONE; layer 0 writes new x to xout (ping-pong) so gathers
// of other blocks never race the x update.
// ---------------------------------------------------------------------------
__global__ __launch_bounds__(256) void fused_layer_kernel(
    const int* __restrict__ row_ptr, const int2* __restrict__ edges,
    const unsigned* __restrict__ xin, unsigned* __restrict__ xout,
    const unsigned* __restrict__ w1b, const unsigned* __restrict__ w2b,
    const float* __restrict__ b1, const float* __restrict__ b2,
    float* __restrict__ out, int outoff, int write_x)
{
    __shared__ __align__(16) unsigned sA1[64 * 64];   // 16 KB
    __shared__ __align__(16) unsigned sA2[64 * 64];   // 16 KB
    __shared__ float sPart[256];

    const int t = threadIdx.x;
    const int wave = t >> 6, lane = t & 63;
    const int q = lane >> 4, r = lane & 15;
    const int G = t >> 4;          // 16-lane group 0..15 (4 per wave)
    const int l = t & 15;          // lane within group
    const int colbase = wave * 32;
    const int base = blockIdx.x * 64;
    const uint4* xin4 = (const uint4*)xin;

    // ---- Phase 1: gather side rows, build A-frags into LDS
    for (int nn = 0; nn < 4; ++nn) {
        const int n = G * 4 + nn;            // local node 0..63
        const int node = base + n;
        float s0=0.f,s1=0.f,s2=0.f,s3=0.f,s4=0.f,s5=0.f,s6=0.f,s7=0.f;
        float x0=0.f,x1=0.f,x2=0.f,x3=0.f,x4=0.f,x5=0.f,x6=0.f,x7=0.f;
        if (node < N_NODES) {
            const int beg = row_ptr[node], end = row_ptr[node + 1];
            const int cnt = end - beg;
            const int nb = cnt >> 4;
            #define GEDGE(u) { \
                int col = __shfl(e.x, (u), 16); \
                float v = __int_as_float(__shfl(e.y, (u), 16)); \
                uint4 xv = xin4[(size_t)col * 16 + l]; \
                float lo, hi; \
                UNPK(xv.x, lo, hi); s0 += v * lo; s1 += v * hi; \
                UNPK(xv.y, lo, hi); s2 += v * lo; s3 += v * hi; \
                UNPK(xv.z, lo, hi); s4 += v * lo; s5 += v * hi; \
                UNPK(xv.w, lo, hi); s6 += v * lo; s7 += v * hi; }
            for (int b = 0; b < nb; ++b) {
                int2 e = edges[beg + b * 16 + l];   // coalesced 128B per group
                GEDGE(0)  GEDGE(1)  GEDGE(2)  GEDGE(3)
                GEDGE(4)  GEDGE(5)  GEDGE(6)  GEDGE(7)
                GEDGE(8)  GEDGE(9)  GEDGE(10) GEDGE(11)
                GEDGE(12) GEDGE(13) GEDGE(14) GEDGE(15)
            }
            const int rem = cnt & 15;
            if (rem) {
                int idx = beg + nb * 16 + l;
                int2 e = edges[idx < end ? idx : end - 1];
                for (int u = 0; u < rem; ++u) GEDGE(u)
            }
            #undef GEDGE
            uint4 xv = xin4[(size_t)node * 16 + l];
            UNPK(xv.x, x0, x1); UNPK(xv.y, x2, x3);
            UNPK(xv.z, x4, x5); UNPK(xv.w, x6, x7);
        }
        uint4 a1q, a2q;
        a1q.x = cvtpk(s0 + x0, s1 + x1);
        a1q.y = cvtpk(s2 + x2, s3 + x3);
        a1q.z = cvtpk(s4 + x4, s5 + x5);
        a1q.w = cvtpk(s6 + x6, s7 + x7);
        a2q.x = cvtpk(s0 * x0, s1 * x1);
        a2q.y = cvtpk(s2 * x2, s3 * x3);
        a2q.z = cvtpk(s4 * x4, s5 * x5);
        a2q.w = cvtpk(s6 * x6, s7 * x7);
        const int slot = l ^ (n & 7);
        *(uint4*)(sA1 + n * 64 + slot * 4) = a1q;
        *(uint4*)(sA2 + n * 64 + slot * 4) = a2q;
    }

    // ---- B-operand fragments (after gather to limit phase-1 reg pressure)
    bf16x8 Wf[2][2][4];                   // [mat][nt][kk]
    {
        const uint4* w1p = (const uint4*)w1b;
        const uint4* w2p = (const uint4*)w2b;
        #pragma unroll
        for (int nt = 0; nt < 2; ++nt) {
            int j = colbase + nt * 16 + r;
            #pragma unroll
            for (int kk = 0; kk < 4; ++kk) {
                B8 a, b;
                a.q = w1p[j * 16 + kk * 4 + q];
                b.q = w2p[j * 16 + kk * 4 + q];
                Wf[0][nt][kk] = a.v;
                Wf[1][nt][kk] = b.v;
            }
        }
    }
    const float bias0 = b1[colbase + r]      + b2[colbase + r];
    const float bias1 = b1[colbase + 16 + r] + b2[colbase + 16 + r];
    __syncthreads();

    // ---- Phase 2: MFMA off LDS fragments
    f32x4 acc[4][2];
    #pragma unroll
    for (int mt = 0; mt < 4; ++mt) {
        acc[mt][0] = (f32x4){0.f, 0.f, 0.f, 0.f};
        acc[mt][1] = (f32x4){0.f, 0.f, 0.f, 0.f};
    }
    int slotk[4];
    {
        const int sw = r & 7;
        #pragma unroll
        for (int kk = 0; kk < 4; ++kk) slotk[kk] = ((kk * 4 + q) ^ sw) * 4;
    }
    #pragma unroll
    for (int mt = 0; mt < 4; ++mt) {
        const unsigned* p1 = sA1 + (mt * 16 + r) * 64;
        const unsigned* p2 = sA2 + (mt * 16 + r) * 64;
        #pragma unroll
        for (int kk = 0; kk < 4; ++kk) {
            B8 a1, a2;
            a1.q = *(const uint4*)(p1 + slotk[kk]);
            a2.q = *(const uint4*)(p2 + slotk[kk]);
            acc[mt][0] = __builtin_amdgcn_mfma_f32_16x16x32_bf16(a1.v, Wf[0][0][kk], acc[mt][0], 0, 0, 0);
            acc[mt][0] = __builtin_amdgcn_mfma_f32_16x16x32_bf16(a2.v, Wf[1][0][kk], acc[mt][0], 0, 0, 0);
            acc[mt][1] = __builtin_amdgcn_mfma_f32_16x16x32_bf16(a1.v, Wf[0][1][kk], acc[mt][1], 0, 0, 0);
            acc[mt][1] = __builtin_amdgcn_mfma_f32_16x16x32_bf16(a2.v, Wf[1][1][kk], acc[mt][1], 0, 0, 0);
        }
    }

    // ---- bias + leaky_relu; per-node partial square-sums (this wave's 32 cols)
    // C/D layout: col = lane&15, row = q*4 + reg  -> node = base+mt*16+q*4+i
    #pragma unroll
    for (int mt = 0; mt < 4; ++mt) {
        #pragma unroll
        for (int i = 0; i < 4; ++i) {
            float y0 = acc[mt][0][i] + bias0; y0 = (y0 >= 0.f) ? y0 : 0.01f * y0;
            float y1 = acc[mt][1][i] + bias1; y1 = (y1 >= 0.f) ? y1 : 0.01f * y1;
            acc[mt][0][i] = y0; acc[mt][1][i] = y1;
            float s = y0 * y0 + y1 * y1;
            s += __shfl_xor(s, 1); s += __shfl_xor(s, 2);
            s += __shfl_xor(s, 4); s += __shfl_xor(s, 8);   // reduce 16 lanes (same q)
            if (r == 0) sPart[wave * 64 + mt * 16 + q * 4 + i] = s;
        }
    }
    __syncthreads();

    // ---- total norm, scale, store
    #pragma unroll
    for (int mt = 0; mt < 4; ++mt) {
        #pragma unroll
        for (int i = 0; i < 4; ++i) {
            int nl = mt * 16 + q * 4 + i;
            float tot = sPart[nl] + sPart[64 + nl] + sPart[128 + nl] + sPart[192 + nl];
            float inv = 1.0f / fmaxf(sqrtf(tot), 1e-12f);
            int node = base + nl;
            if (node < N_NODES) {
                float y0 = acc[mt][0][i] * inv;
                float y1 = acc[mt][1][i] * inv;
                out[(size_t)node * 384 + outoff + colbase + r]      = y0;
                out[(size_t)node * 384 + outoff + colbase + 16 + r] = y1;
                if (write_x) {
                    ((unsigned short*)xout)[(size_t)node * 128 + colbase + r]      = f2bs(y0);
                    ((unsigned short*)xout)[(size_t)node * 128 + colbase + 16 + r] = f2bs(y1);
                }
            }
        }
    }
}

// ---------------------------------------------------------------------------
extern "C" void kernel_launch(void* const* d_in, const int* in_sizes, int n_in,
                              void* d_out, int out_size, void* d_ws, size_t ws_size,
                              hipStream_t stream)
{
    const int*   adj_row  = (const int*)d_in[0];
    const int*   adj_col  = (const int*)d_in[1];
    const float* adj_vals = (const float*)d_in[2];
    const float* emb      = (const float*)d_in[3];
    const float* W1_w     = (const float*)d_in[4];
    const float* W1_b     = (const float*)d_in[5];
    const float* W2_w     = (const float*)d_in[6];
    const float* W2_b     = (const float*)d_in[7];
    float* out = (float*)d_out;

    // ---- workspace layout (bytes; all 16B-aligned). Total ~64.95 MB.
    uint8_t* w = (uint8_t*)d_ws;
    unsigned* xA      = (unsigned*)(w);                 // NPAD*128 bf16 = 25,608,192 B
    unsigned* xB      = (unsigned*)(w + 25608192);      // ping-pong x (old sideb slot)
    int2*     edges   = (int2*)    (w + 51216384);      // NNZ*8 = 12,800,000 B
    unsigned* w1b     = (unsigned*)(w + 64016384);      // 2*128*128 bf16 = 65,536 B
    unsigned* w2b     = (unsigned*)(w + 64081920);      // 65,536 B
    int*      row_ptr = (int*)     (w + 64147456);      // (N+1)*4
    int*      cnt     = (int*)     (w + 64547472);      // N*4 (hist counts, then countdown)
    int*      tsums   = (int*)     (w + 64947488);      // N_TILES*4

    prep_kernel<<<128, 256, 0, stream>>>(W1_w, W2_w, w1b, w2b, cnt);
    copy_emb_kernel<<<NPAD * 32 / 256, 256, 0, stream>>>(emb, out, xA);

    // ---- CSR build (no memsets: prep zeroed cnt; scatter counts it back down)
    hist_kernel<<<NNZ_E / 256, 256, 0, stream>>>(adj_row, cnt);
    scan_pass_a<<<N_TILES, 256, 0, stream>>>(cnt, tsums);
    scan_pass_b<<<1, 64, 0, stream>>>(tsums);
    scan_pass_c<<<N_TILES, 256, 0, stream>>>(cnt, tsums, row_ptr);
    scatter_kernel<<<NNZ_E / 256, 256, 0, stream>>>(
        adj_row, adj_col, adj_vals, row_ptr, cnt, edges);

    // ---- fused layers: L0 reads xA writes xB (+out[:,128:256]);
    //                    L1 reads xB (+out[:,256:384])
    fused_layer_kernel<<<NPAD / 64, 256, 0, stream>>>(
        row_ptr, edges, xA, xB, w1b, w2b, W1_b, W2_b, out, DIM, 1);
    fused_layer_kernel<<<NPAD / 64, 256, 0, stream>>>(
        row_ptr, edges, xB, xB, w1b + 8192, w2b + 8192,
        W1_b + DIM, W2_b + DIM, out, 2 * DIM, 0);
}

// Round 4
// 672.868 us; speedup vs baseline: 1.0304x; 1.0304x over previous
//
#include <hip/hip_runtime.h>
#include <stdint.h>

#define N_NODES 100000
#define NPAD    100032
#define DIM 128
#define NNZ_E 1600000
#define SCAN_TILE 2048
#define N_TILES ((N_NODES + SCAN_TILE - 1) / SCAN_TILE)   // 49

typedef float f32x4  __attribute__((ext_vector_type(4)));
typedef short bf16x8 __attribute__((ext_vector_type(8)));

union B8 { uint4 q; unsigned u[4]; bf16x8 v; };

__device__ __forceinline__ unsigned short f2bs(float f) {   // fp32 -> bf16 RNE
    unsigned u = __builtin_bit_cast(unsigned, f);
    u = (u + 0x7fffu + ((u >> 16) & 1u)) >> 16;
    return (unsigned short)u;
}
// HW packed fp32->bf16 RNE convert: 1 instruction replaces ~8
__device__ __forceinline__ unsigned cvtpk(float lo, float hi) {
    unsigned r;
    asm("v_cvt_pk_bf16_f32 %0, %1, %2" : "=v"(r) : "v"(lo), "v"(hi));
    return r;
}
#define UNPK(u32, flo, fhi) { flo = __builtin_bit_cast(float, (unsigned)((u32) << 16)); \
                              fhi = __builtin_bit_cast(float, (unsigned)((u32) & 0xffff0000u)); }

// ---------------------------------------------------------------------------
// emb -> out[:,0:128] fp32  AND  xbuf bf16 (pad rows zeroed here: no memset)
// ---------------------------------------------------------------------------
__global__ __launch_bounds__(256) void copy_emb_kernel(
    const float* __restrict__ emb, float* __restrict__ out,
    unsigned* __restrict__ xbuf)
{
    int tid = blockIdx.x * 256 + threadIdx.x;   // NPAD*32 threads, one float4 each
    int n = tid >> 5, c = tid & 31;
    if (n < N_NODES) {
        float4 v = ((const float4*)emb)[tid];
        *((float4*)(out + (size_t)n * 384) + c) = v;
        ((uint2*)xbuf)[(size_t)n * 32 + c] = make_uint2(cvtpk(v.x, v.y), cvtpk(v.z, v.w));
    } else {
        ((uint2*)xbuf)[(size_t)n * 32 + c] = make_uint2(0u, 0u);
    }
}

// ---------------------------------------------------------------------------
// Fused prep: W fp32 -> bf16 (both layers, both matrices) + zero cnt.
// ---------------------------------------------------------------------------
__global__ __launch_bounds__(256) void prep_kernel(
    const float* __restrict__ W1, const float* __restrict__ W2,
    unsigned* __restrict__ w1b, unsigned* __restrict__ w2b,
    int* __restrict__ cnt)
{
    int tid = blockIdx.x * 256 + threadIdx.x;
    if (tid < 8192) {
        float4 a = ((const float4*)W1)[tid];
        float4 b = ((const float4*)W2)[tid];
        ((uint2*)w1b)[tid] = make_uint2(cvtpk(a.x, a.y), cvtpk(a.z, a.w));
        ((uint2*)w2b)[tid] = make_uint2(cvtpk(b.x, b.y), cvtpk(b.z, b.w));
    }
    if (tid < 25000) ((uint4*)cnt)[tid] = make_uint4(0u, 0u, 0u, 0u);  // 100000 ints
}

// ---------------------------------------------------------------------------
// CSR build: histogram -> scan -> countdown scatter
// ---------------------------------------------------------------------------
__global__ __launch_bounds__(256) void hist_kernel(
    const int* __restrict__ rows, int* __restrict__ cnt)
{
    int e = blockIdx.x * 256 + threadIdx.x;
    atomicAdd(&cnt[rows[e]], 1);
}

__global__ __launch_bounds__(256) void scan_pass_a(
    const int* __restrict__ cnt, int* __restrict__ tile_sums)
{
    __shared__ int sdata[256];
    int base = blockIdx.x * SCAN_TILE + threadIdx.x * 8;
    int s = 0;
    #pragma unroll
    for (int q = 0; q < 8; ++q) {
        int i = base + q;
        s += (i < N_NODES) ? cnt[i] : 0;
    }
    sdata[threadIdx.x] = s;
    __syncthreads();
    for (int off = 128; off >= 1; off >>= 1) {
        if (threadIdx.x < off) sdata[threadIdx.x] += sdata[threadIdx.x + off];
        __syncthreads();
    }
    if (threadIdx.x == 0) tile_sums[blockIdx.x] = sdata[0];
}

// wave-parallel exclusive scan over 49 tile sums
__global__ void scan_pass_b(int* __restrict__ tile_sums)
{
    int lane = threadIdx.x;          // 64 lanes
    int v = (lane < N_TILES) ? tile_sums[lane] : 0;
    #pragma unroll
    for (int off = 1; off < 64; off <<= 1) {
        int u = __shfl_up(v, off);
        if (lane >= off) v += u;
    }
    int ex = __shfl_up(v, 1);
    if (lane == 0) ex = 0;
    if (lane < N_TILES) tile_sums[lane] = ex;
}

__global__ __launch_bounds__(256) void scan_pass_c(
    const int* __restrict__ cnt, const int* __restrict__ tile_offs,
    int* __restrict__ row_ptr)
{
    __shared__ int spart[256];
    int t = threadIdx.x;
    int base = blockIdx.x * SCAN_TILE + t * 8;
    int loc[8];
    int s = 0;
    #pragma unroll
    for (int q = 0; q < 8; ++q) {
        int i = base + q;
        int c = (i < N_NODES) ? cnt[i] : 0;
        loc[q] = s; s += c;
    }
    spart[t] = s;
    __syncthreads();
    for (int off = 1; off < 256; off <<= 1) {
        int v = (t >= off) ? spart[t - off] : 0;
        __syncthreads();
        spart[t] += v;
        __syncthreads();
    }
    int exoff = tile_offs[blockIdx.x] + spart[t] - s;
    #pragma unroll
    for (int q = 0; q < 8; ++q) {
        int i = base + q;
        if (i <= N_NODES) row_ptr[i] = exoff + loc[q];
    }
}

// scatter via countdown on cnt (scan passes only READ cnt) -> no second memset
__global__ __launch_bounds__(256) void scatter_kernel(
    const int* __restrict__ rows, const int* __restrict__ cols,
    const float* __restrict__ vals, const int* __restrict__ row_ptr,
    int* __restrict__ cnt, int2* __restrict__ edges)
{
    int e = blockIdx.x * 256 + threadIdx.x;
    int r = rows[e];
    int pos = row_ptr[r] + atomicSub(&cnt[r], 1) - 1;
    edges[pos] = make_int2(cols[e], __float_as_int(vals[e]));
}

// ---------------------------------------------------------------------------
// Gather SpMM (bf16 x -> bf16 side): one wave per row.
// Branchless chunks-of-8 with index-clamped dummy loads (val=0 past end,
// address clamped to beg -> cache-hit). Next chunk's gathers are issued
// BEFORE consuming the current chunk: 8-16 outstanding loads per wave at all
// times, no serial tail (was: serial 1-deep tail of up to 7 edges).
// Grid covers NPAD: pad rows write zeros (replaces memset).
// ---------------------------------------------------------------------------
__global__ __launch_bounds__(256) void spmm_gather_bf16(
    const int* __restrict__ row_ptr, const int2* __restrict__ edges,
    const unsigned* __restrict__ xb, unsigned* __restrict__ sideb)
{
    int row  = blockIdx.x * 4 + (threadIdx.x >> 6);
    int lane = threadIdx.x & 63;
    if (row >= N_NODES) {                       // pad rows (< NPAD): zero
        sideb[(size_t)row * 64 + lane] = 0u;
        return;
    }
    int beg = row_ptr[row], end = row_ptr[row + 1];
    int nc = (end - beg + 7) >> 3;              // number of 8-chunks (0 if empty)
    float ax = 0.f, ay = 0.f;
    if (nc) {
        unsigned g[8]; float v[8];
        #pragma unroll
        for (int u = 0; u < 8; ++u) {           // chunk 0: clamped load + issue
            int idx = beg + u;
            bool ok = idx < end;
            int2 d = edges[ok ? idx : beg];
            v[u] = ok ? __int_as_float(d.y) : 0.f;
            g[u] = xb[(size_t)d.x * 64 + lane];
        }
        for (int c = 1; c < nc; ++c) {
            unsigned g2[8]; float v2[8];
            int cb = beg + c * 8;
            #pragma unroll
            for (int u = 0; u < 8; ++u) {       // issue chunk c gathers first
                int idx = cb + u;
                bool ok = idx < end;
                int2 d = edges[ok ? idx : beg];
                v2[u] = ok ? __int_as_float(d.y) : 0.f;
                g2[u] = xb[(size_t)d.x * 64 + lane];
            }
            #pragma unroll
            for (int u = 0; u < 8; ++u) {       // consume chunk c-1
                float lo, hi;
                UNPK(g[u], lo, hi); ax += v[u] * lo; ay += v[u] * hi;
            }
            #pragma unroll
            for (int u = 0; u < 8; ++u) { g[u] = g2[u]; v[u] = v2[u]; }
        }
        #pragma unroll
        for (int u = 0; u < 8; ++u) {           // consume last chunk
            float lo, hi;
            UNPK(g[u], lo, hi); ax += v[u] * lo; ay += v[u] * hi;
        }
    }
    sideb[(size_t)row * 64 + lane] = cvtpk(ax, ay);
}

// ---------------------------------------------------------------------------
// MFMA dense: Y = leaky_relu((side+x)@W1^T + (side*x)@W2^T + b1 + b2), L2-norm
// rows, write fp32 to out[:, outoff:+128]; if write_x, also rewrite xbuf (bf16).
//
// Phase 1: 256 threads build a1=(s+x), a2=(s*x) bf16 fragments ONCE into LDS.
//          XOR-swizzle slot ^= (node&7): ds_write_b128 and ds_read_b128 both
//          conflict-free.
// Phase 2: wave w owns cols [w*32,+32); 4 MFMAs per (mt,kk) off ds_read_b128.
// ---------------------------------------------------------------------------
__global__ __launch_bounds__(256) void dense_mfma_kernel(
    const unsigned* __restrict__ sideb, unsigned* __restrict__ xbuf,
    const unsigned* __restrict__ w1b, const unsigned* __restrict__ w2b,
    const float* __restrict__ b1, const float* __restrict__ b2,
    float* __restrict__ out, int outoff, int write_x)
{
    __shared__ __align__(16) unsigned sA1[64 * 64];   // 16 KB
    __shared__ __align__(16) unsigned sA2[64 * 64];   // 16 KB
    __shared__ float sPart[256];

    const int t = threadIdx.x;
    const int wave = t >> 6, lane = t & 63;
    const int q = lane >> 4, r = lane & 15;
    const int colbase = wave * 32;
    const int base = blockIdx.x * 64;

    // ---- B-operand fragments: lane holds W[j = colbase+nt*16+r][kk*32+q*8 ..+8)
    bf16x8 Wf[2][2][4];                   // [mat][nt][kk]
    {
        const uint4* w1p = (const uint4*)w1b;
        const uint4* w2p = (const uint4*)w2b;
        #pragma unroll
        for (int nt = 0; nt < 2; ++nt) {
            int j = colbase + nt * 16 + r;
            #pragma unroll
            for (int kk = 0; kk < 4; ++kk) {
                B8 a, b;
                a.q = w1p[j * 16 + kk * 4 + q];
                b.q = w2p[j * 16 + kk * 4 + q];
                Wf[0][nt][kk] = a.v;
                Wf[1][nt][kk] = b.v;
            }
        }
    }
    const float bias0 = b1[colbase + r]      + b2[colbase + r];
    const float bias1 = b1[colbase + 16 + r] + b2[colbase + 16 + r];

    // ---- Phase 1: build A-frags into LDS. thread t: node t>>2, 64B seg t&3.
    {
        const int n = t >> 2, seg = t & 3;
        const uint4* sp = (const uint4*)sideb + ((size_t)(base + n)) * 16 + seg * 4;
        const uint4* xp = (const uint4*)xbuf  + ((size_t)(base + n)) * 16 + seg * 4;
        unsigned* d1 = sA1 + n * 64;
        unsigned* d2 = sA2 + n * 64;
        const int sw = n & 7, seg4 = seg * 4;
        #pragma unroll
        for (int j = 0; j < 4; ++j) {
            uint4 sv = sp[j];
            uint4 xv = xp[j];
            float s0,s1,s2,s3,s4,s5,s6,s7;
            float x0,x1,x2,x3,x4,x5,x6,x7;
            UNPK(sv.x, s0, s1); UNPK(sv.y, s2, s3);
            UNPK(sv.z, s4, s5); UNPK(sv.w, s6, s7);
            UNPK(xv.x, x0, x1); UNPK(xv.y, x2, x3);
            UNPK(xv.z, x4, x5); UNPK(xv.w, x6, x7);
            uint4 a1q, a2q;
            a1q.x = cvtpk(s0 + x0, s1 + x1);
            a1q.y = cvtpk(s2 + x2, s3 + x3);
            a1q.z = cvtpk(s4 + x4, s5 + x5);
            a1q.w = cvtpk(s6 + x6, s7 + x7);
            a2q.x = cvtpk(s0 * x0, s1 * x1);
            a2q.y = cvtpk(s2 * x2, s3 * x3);
            a2q.z = cvtpk(s4 * x4, s5 * x5);
            a2q.w = cvtpk(s6 * x6, s7 * x7);
            int slot = (seg4 + j) ^ sw;
            *(uint4*)(d1 + slot * 4) = a1q;
            *(uint4*)(d2 + slot * 4) = a2q;
        }
    }
    __syncthreads();

    // ---- Phase 2: MFMA off LDS fragments
    f32x4 acc[4][2];
    #pragma unroll
    for (int mt = 0; mt < 4; ++mt) {
        acc[mt][0] = (f32x4){0.f, 0.f, 0.f, 0.f};
        acc[mt][1] = (f32x4){0.f, 0.f, 0.f, 0.f};
    }
    int slotk[4];
    {
        const int sw = r & 7;
        #pragma unroll
        for (int kk = 0; kk < 4; ++kk) slotk[kk] = ((kk * 4 + q) ^ sw) * 4;
    }
    #pragma unroll
    for (int mt = 0; mt < 4; ++mt) {
        const unsigned* p1 = sA1 + (mt * 16 + r) * 64;
        const unsigned* p2 = sA2 + (mt * 16 + r) * 64;
        #pragma unroll
        for (int kk = 0; kk < 4; ++kk) {
            B8 a1, a2;
            a1.q = *(const uint4*)(p1 + slotk[kk]);
            a2.q = *(const uint4*)(p2 + slotk[kk]);
            acc[mt][0] = __builtin_amdgcn_mfma_f32_16x16x32_bf16(a1.v, Wf[0][0][kk], acc[mt][0], 0, 0, 0);
            acc[mt][0] = __builtin_amdgcn_mfma_f32_16x16x32_bf16(a2.v, Wf[1][0][kk], acc[mt][0], 0, 0, 0);
            acc[mt][1] = __builtin_amdgcn_mfma_f32_16x16x32_bf16(a1.v, Wf[0][1][kk], acc[mt][1], 0, 0, 0);
            acc[mt][1] = __builtin_amdgcn_mfma_f32_16x16x32_bf16(a2.v, Wf[1][1][kk], acc[mt][1], 0, 0, 0);
        }
    }

    // ---- bias + leaky_relu; per-node partial square-sums (this wave's 32 cols)
    // C/D layout: col = lane&15, row = q*4 + reg  -> node = base+mt*16+q*4+i
    #pragma unroll
    for (int mt = 0; mt < 4; ++mt) {
        #pragma unroll
        for (int i = 0; i < 4; ++i) {
            float y0 = acc[mt][0][i] + bias0; y0 = (y0 >= 0.f) ? y0 : 0.01f * y0;
            float y1 = acc[mt][1][i] + bias1; y1 = (y1 >= 0.f) ? y1 : 0.01f * y1;
            acc[mt][0][i] = y0; acc[mt][1][i] = y1;
            float s = y0 * y0 + y1 * y1;
            s += __shfl_xor(s, 1); s += __shfl_xor(s, 2);
            s += __shfl_xor(s, 4); s += __shfl_xor(s, 8);   // reduce 16 lanes (same q)
            if (r == 0) sPart[wave * 64 + mt * 16 + q * 4 + i] = s;
        }
    }
    __syncthreads();

    // ---- total norm, scale, store
    #pragma unroll
    for (int mt = 0; mt < 4; ++mt) {
        #pragma unroll
        for (int i = 0; i < 4; ++i) {
            int nl = mt * 16 + q * 4 + i;
            float tot = sPart[nl] + sPart[64 + nl] + sPart[128 + nl] + sPart[192 + nl];
            float inv = 1.0f / fmaxf(sqrtf(tot), 1e-12f);
            int node = base + nl;
            if (node < N_NODES) {
                float y0 = acc[mt][0][i] * inv;
                float y1 = acc[mt][1][i] * inv;
                out[(size_t)node * 384 + outoff + colbase + r]      = y0;
                out[(size_t)node * 384 + outoff + colbase + 16 + r] = y1;
                if (write_x) {
                    ((unsigned short*)xbuf)[(size_t)node * 128 + colbase + r]      = f2bs(y0);
                    ((unsigned short*)xbuf)[(size_t)node * 128 + colbase + 16 + r] = f2bs(y1);
                }
            }
        }
    }
}

// ---------------------------------------------------------------------------
extern "C" void kernel_launch(void* const* d_in, const int* in_sizes, int n_in,
                              void* d_out, int out_size, void* d_ws, size_t ws_size,
                              hipStream_t stream)
{
    const int*   adj_row  = (const int*)d_in[0];
    const int*   adj_col  = (const int*)d_in[1];
    const float* adj_vals = (const float*)d_in[2];
    const float* emb      = (const float*)d_in[3];
    const float* W1_w     = (const float*)d_in[4];
    const float* W1_b     = (const float*)d_in[5];
    const float* W2_w     = (const float*)d_in[6];
    const float* W2_b     = (const float*)d_in[7];
    float* out = (float*)d_out;

    // ---- workspace layout (bytes; all 16B-aligned). Total ~64.95 MB.
    uint8_t* w = (uint8_t*)d_ws;
    unsigned* xbuf    = (unsigned*)(w);                 // NPAD*128 bf16 = 25,608,192 B
    unsigned* sideb   = (unsigned*)(w + 25608192);      // NPAD*128 bf16
    int2*     edges   = (int2*)    (w + 51216384);      // NNZ*8 = 12,800,000 B
    unsigned* w1b     = (unsigned*)(w + 64016384);      // 2*128*128 bf16 = 65,536 B
    unsigned* w2b     = (unsigned*)(w + 64081920);      // 65,536 B
    int*      row_ptr = (int*)     (w + 64147456);      // (N+1)*4
    int*      cnt     = (int*)     (w + 64547472);      // N*4 (hist counts, then countdown)
    int*      tsums   = (int*)     (w + 64947488);      // N_TILES*4

    prep_kernel<<<128, 256, 0, stream>>>(W1_w, W2_w, w1b, w2b, cnt);
    copy_emb_kernel<<<NPAD * 32 / 256, 256, 0, stream>>>(emb, out, xbuf);

    // ---- CSR build (no memsets: prep zeroed cnt; scatter counts it back down)
    hist_kernel<<<NNZ_E / 256, 256, 0, stream>>>(adj_row, cnt);
    scan_pass_a<<<N_TILES, 256, 0, stream>>>(cnt, tsums);
    scan_pass_b<<<1, 64, 0, stream>>>(tsums);
    scan_pass_c<<<N_TILES, 256, 0, stream>>>(cnt, tsums, row_ptr);
    scatter_kernel<<<NNZ_E / 256, 256, 0, stream>>>(
        adj_row, adj_col, adj_vals, row_ptr, cnt, edges);

    for (int k = 0; k < 2; ++k) {
        spmm_gather_bf16<<<NPAD / 4, 256, 0, stream>>>(row_ptr, edges, xbuf, sideb);
        dense_mfma_kernel<<<NPAD / 64, 256, 0, stream>>>(
            sideb, xbuf, w1b + k * 8192, w2b + k * 8192,
            W1_b + k * DIM, W2_b + k * DIM,
            out, DIM * (k + 1), (k == 0) ? 1 : 0);
    }
}

// Round 5
// 571.469 us; speedup vs baseline: 1.2132x; 1.1774x over previous
//
#include <hip/hip_runtime.h>
#include <stdint.h>

#define N_NODES 100000
#define NPAD    100032
#define DIM 128
#define NNZ_E 1600000
#define SCAN_TILE 2048
#define N_TILES ((N_NODES + SCAN_TILE - 1) / SCAN_TILE)   // 49

typedef float f32x4  __attribute__((ext_vector_type(4)));
typedef short bf16x8 __attribute__((ext_vector_type(8)));

union B8 { uint4 q; unsigned u[4]; bf16x8 v; };

__device__ __forceinline__ unsigned short f2bs(float f) {   // fp32 -> bf16 RNE
    unsigned u = __builtin_bit_cast(unsigned, f);
    u = (u + 0x7fffu + ((u >> 16) & 1u)) >> 16;
    return (unsigned short)u;
}
// HW packed fp32->bf16 RNE convert: 1 instruction replaces ~8
__device__ __forceinline__ unsigned cvtpk(float lo, float hi) {
    unsigned r;
    asm("v_cvt_pk_bf16_f32 %0, %1, %2" : "=v"(r) : "v"(lo), "v"(hi));
    return r;
}
#define UNPK(u32, flo, fhi) { flo = __builtin_bit_cast(float, (unsigned)((u32) << 16)); \
                              fhi = __builtin_bit_cast(float, (unsigned)((u32) & 0xffff0000u)); }

// ---------------------------------------------------------------------------
// emb -> out[:,0:128] fp32  AND  xbuf bf16 (pad rows zeroed here: no memset)
// ---------------------------------------------------------------------------
__global__ __launch_bounds__(256) void copy_emb_kernel(
    const float* __restrict__ emb, float* __restrict__ out,
    unsigned* __restrict__ xbuf)
{
    int tid = blockIdx.x * 256 + threadIdx.x;   // NPAD*32 threads, one float4 each
    int n = tid >> 5, c = tid & 31;
    if (n < N_NODES) {
        float4 v = ((const float4*)emb)[tid];
        *((float4*)(out + (size_t)n * 384) + c) = v;
        ((uint2*)xbuf)[(size_t)n * 32 + c] = make_uint2(cvtpk(v.x, v.y), cvtpk(v.z, v.w));
    } else {
        ((uint2*)xbuf)[(size_t)n * 32 + c] = make_uint2(0u, 0u);
    }
}

// ---------------------------------------------------------------------------
// Fused prep: W fp32 -> bf16 (both layers, both matrices) + zero cnt.
// ---------------------------------------------------------------------------
__global__ __launch_bounds__(256) void prep_kernel(
    const float* __restrict__ W1, const float* __restrict__ W2,
    unsigned* __restrict__ w1b, unsigned* __restrict__ w2b,
    int* __restrict__ cnt)
{
    int tid = blockIdx.x * 256 + threadIdx.x;
    if (tid < 8192) {
        float4 a = ((const float4*)W1)[tid];
        float4 b = ((const float4*)W2)[tid];
        ((uint2*)w1b)[tid] = make_uint2(cvtpk(a.x, a.y), cvtpk(a.z, a.w));
        ((uint2*)w2b)[tid] = make_uint2(cvtpk(b.x, b.y), cvtpk(b.z, b.w));
    }
    if (tid < 25000) ((uint4*)cnt)[tid] = make_uint4(0u, 0u, 0u, 0u);  // 100000 ints
}

// ---------------------------------------------------------------------------
// CSR build: histogram -> scan -> countdown scatter
// ---------------------------------------------------------------------------
__global__ __launch_bounds__(256) void hist_kernel(
    const int* __restrict__ rows, int* __restrict__ cnt)
{
    int e = blockIdx.x * 256 + threadIdx.x;
    atomicAdd(&cnt[rows[e]], 1);
}

__global__ __launch_bounds__(256) void scan_pass_a(
    const int* __restrict__ cnt, int* __restrict__ tile_sums)
{
    __shared__ int sdata[256];
    int base = blockIdx.x * SCAN_TILE + threadIdx.x * 8;
    int s = 0;
    #pragma unroll
    for (int q = 0; q < 8; ++q) {
        int i = base + q;
        s += (i < N_NODES) ? cnt[i] : 0;
    }
    sdata[threadIdx.x] = s;
    __syncthreads();
    for (int off = 128; off >= 1; off >>= 1) {
        if (threadIdx.x < off) sdata[threadIdx.x] += sdata[threadIdx.x + off];
        __syncthreads();
    }
    if (threadIdx.x == 0) tile_sums[blockIdx.x] = sdata[0];
}

// wave-parallel exclusive scan over 49 tile sums
__global__ void scan_pass_b(int* __restrict__ tile_sums)
{
    int lane = threadIdx.x;          // 64 lanes
    int v = (lane < N_TILES) ? tile_sums[lane] : 0;
    #pragma unroll
    for (int off = 1; off < 64; off <<= 1) {
        int u = __shfl_up(v, off);
        if (lane >= off) v += u;
    }
    int ex = __shfl_up(v, 1);
    if (lane == 0) ex = 0;
    if (lane < N_TILES) tile_sums[lane] = ex;
}

__global__ __launch_bounds__(256) void scan_pass_c(
    const int* __restrict__ cnt, const int* __restrict__ tile_offs,
    int* __restrict__ row_ptr)
{
    __shared__ int spart[256];
    int t = threadIdx.x;
    int base = blockIdx.x * SCAN_TILE + t * 8;
    int loc[8];
    int s = 0;
    #pragma unroll
    for (int q = 0; q < 8; ++q) {
        int i = base + q;
        int c = (i < N_NODES) ? cnt[i] : 0;
        loc[q] = s; s += c;
    }
    spart[t] = s;
    __syncthreads();
    for (int off = 1; off < 256; off <<= 1) {
        int v = (t >= off) ? spart[t - off] : 0;
        __syncthreads();
        spart[t] += v;
        __syncthreads();
    }
    int exoff = tile_offs[blockIdx.x] + spart[t] - s;
    #pragma unroll
    for (int q = 0; q < 8; ++q) {
        int i = base + q;
        if (i <= N_NODES) row_ptr[i] = exoff + loc[q];
    }
}

// scatter via countdown on cnt (scan passes only READ cnt) -> no second memset
__global__ __launch_bounds__(256) void scatter_kernel(
    const int* __restrict__ rows, const int* __restrict__ cols,
    const float* __restrict__ vals, const int* __restrict__ row_ptr,
    int* __restrict__ cnt, int2* __restrict__ edges)
{
    int e = blockIdx.x * 256 + threadIdx.x;
    int r = rows[e];
    int pos = row_ptr[r] + atomicSub(&cnt[r], 1) - 1;
    edges[pos] = make_int2(cols[e], __float_as_int(vals[e]));
}

// ---------------------------------------------------------------------------
// Gather SpMM (bf16 x -> bf16 side): TWO rows per wave, 32 lanes each, one
// uint2 (4 bf16 cols, 8 B) per lane -> every wave instruction (desc load,
// addr calc, gather, unpack, FMA) serves 2 edges. Round-1 pipeline structure:
// 8-deep descriptor prefetch, gathers scheduled ahead by unroll, serial tail
// (no dummy loads, no clamp cndmask -- the round-3 clamped version regressed).
// Grid covers NPAD: pad rows write zeros (replaces memset).
// ---------------------------------------------------------------------------
__global__ __launch_bounds__(256) void spmm_gather_bf16(
    const int* __restrict__ row_ptr, const int2* __restrict__ edges,
    const uint2* __restrict__ xb2, uint2* __restrict__ side2)
{
    const int lane = threadIdx.x & 63;
    const int hl   = lane & 31;                 // lane within half-wave
    const int row  = blockIdx.x * 8 + ((threadIdx.x >> 6) << 1) + (lane >> 5);
    if (row >= N_NODES) {                       // pad rows (< NPAD): zero
        side2[(size_t)row * 32 + hl] = make_uint2(0u, 0u);
        return;
    }
    const int beg = row_ptr[row], end = row_ptr[row + 1];
    float a0 = 0.f, a1 = 0.f, a2 = 0.f, a3 = 0.f;
    int i = beg;
    const int nfull = (end - beg) & ~7;
    if (nfull) {
        int2 e[8];
        #pragma unroll
        for (int u = 0; u < 8; ++u) e[u] = edges[i + u];
        for (int g = 8; g < nfull; g += 8) {
            int2 f[8];
            #pragma unroll
            for (int u = 0; u < 8; ++u) f[u] = edges[i + 8 + u];
            #pragma unroll
            for (int u = 0; u < 8; ++u) {
                uint2 xv = xb2[(size_t)e[u].x * 32 + hl];
                float v = __int_as_float(e[u].y), lo, hi;
                UNPK(xv.x, lo, hi); a0 += v * lo; a1 += v * hi;
                UNPK(xv.y, lo, hi); a2 += v * lo; a3 += v * hi;
            }
            #pragma unroll
            for (int u = 0; u < 8; ++u) e[u] = f[u];
            i += 8;
        }
        #pragma unroll
        for (int u = 0; u < 8; ++u) {
            uint2 xv = xb2[(size_t)e[u].x * 32 + hl];
            float v = __int_as_float(e[u].y), lo, hi;
            UNPK(xv.x, lo, hi); a0 += v * lo; a1 += v * hi;
            UNPK(xv.y, lo, hi); a2 += v * lo; a3 += v * hi;
        }
        i += 8;
    }
    for (; i < end; ++i) {
        int2 e = edges[i];
        uint2 xv = xb2[(size_t)e.x * 32 + hl];
        float v = __int_as_float(e.y), lo, hi;
        UNPK(xv.x, lo, hi); a0 += v * lo; a1 += v * hi;
        UNPK(xv.y, lo, hi); a2 += v * lo; a3 += v * hi;
    }
    side2[(size_t)row * 32 + hl] = make_uint2(cvtpk(a0, a1), cvtpk(a2, a3));
}

// ---------------------------------------------------------------------------
// MFMA dense: Y = leaky_relu((side+x)@W1^T + (side*x)@W2^T + b1 + b2), L2-norm
// rows, write fp32 to out[:, outoff:+128]; if write_x, also rewrite xbuf (bf16).
//
// Phase 1: 256 threads build a1=(s+x), a2=(s*x) bf16 fragments ONCE into LDS.
//          XOR-swizzle slot ^= (node&7): ds_write_b128 and ds_read_b128 both
//          conflict-free.
// Phase 2: wave w owns cols [w*32,+32); 4 MFMAs per (mt,kk) off ds_read_b128.
// ---------------------------------------------------------------------------
__global__ __launch_bounds__(256) void dense_mfma_kernel(
    const unsigned* __restrict__ sideb, unsigned* __restrict__ xbuf,
    const unsigned* __restrict__ w1b, const unsigned* __restrict__ w2b,
    const float* __restrict__ b1, const float* __restrict__ b2,
    float* __restrict__ out, int outoff, int write_x)
{
    __shared__ __align__(16) unsigned sA1[64 * 64];   // 16 KB
    __shared__ __align__(16) unsigned sA2[64 * 64];   // 16 KB
    __shared__ float sPart[256];

    const int t = threadIdx.x;
    const int wave = t >> 6, lane = t & 63;
    const int q = lane >> 4, r = lane & 15;
    const int colbase = wave * 32;
    const int base = blockIdx.x * 64;

    // ---- B-operand fragments: lane holds W[j = colbase+nt*16+r][kk*32+q*8 ..+8)
    bf16x8 Wf[2][2][4];                   // [mat][nt][kk]
    {
        const uint4* w1p = (const uint4*)w1b;
        const uint4* w2p = (const uint4*)w2b;
        #pragma unroll
        for (int nt = 0; nt < 2; ++nt) {
            int j = colbase + nt * 16 + r;
            #pragma unroll
            for (int kk = 0; kk < 4; ++kk) {
                B8 a, b;
                a.q = w1p[j * 16 + kk * 4 + q];
                b.q = w2p[j * 16 + kk * 4 + q];
                Wf[0][nt][kk] = a.v;
                Wf[1][nt][kk] = b.v;
            }
        }
    }
    const float bias0 = b1[colbase + r]      + b2[colbase + r];
    const float bias1 = b1[colbase + 16 + r] + b2[colbase + 16 + r];

    // ---- Phase 1: build A-frags into LDS. thread t: node t>>2, 64B seg t&3.
    {
        const int n = t >> 2, seg = t & 3;
        const uint4* sp = (const uint4*)sideb + ((size_t)(base + n)) * 16 + seg * 4;
        const uint4* xp = (const uint4*)xbuf  + ((size_t)(base + n)) * 16 + seg * 4;
        unsigned* d1 = sA1 + n * 64;
        unsigned* d2 = sA2 + n * 64;
        const int sw = n & 7, seg4 = seg * 4;
        #pragma unroll
        for (int j = 0; j < 4; ++j) {
            uint4 sv = sp[j];
            uint4 xv = xp[j];
            float s0,s1,s2,s3,s4,s5,s6,s7;
            float x0,x1,x2,x3,x4,x5,x6,x7;
            UNPK(sv.x, s0, s1); UNPK(sv.y, s2, s3);
            UNPK(sv.z, s4, s5); UNPK(sv.w, s6, s7);
            UNPK(xv.x, x0, x1); UNPK(xv.y, x2, x3);
            UNPK(xv.z, x4, x5); UNPK(xv.w, x6, x7);
            uint4 a1q, a2q;
            a1q.x = cvtpk(s0 + x0, s1 + x1);
            a1q.y = cvtpk(s2 + x2, s3 + x3);
            a1q.z = cvtpk(s4 + x4, s5 + x5);
            a1q.w = cvtpk(s6 + x6, s7 + x7);
            a2q.x = cvtpk(s0 * x0, s1 * x1);
            a2q.y = cvtpk(s2 * x2, s3 * x3);
            a2q.z = cvtpk(s4 * x4, s5 * x5);
            a2q.w = cvtpk(s6 * x6, s7 * x7);
            int slot = (seg4 + j) ^ sw;
            *(uint4*)(d1 + slot * 4) = a1q;
            *(uint4*)(d2 + slot * 4) = a2q;
        }
    }
    __syncthreads();

    // ---- Phase 2: MFMA off LDS fragments
    f32x4 acc[4][2];
    #pragma unroll
    for (int mt = 0; mt < 4; ++mt) {
        acc[mt][0] = (f32x4){0.f, 0.f, 0.f, 0.f};
        acc[mt][1] = (f32x4){0.f, 0.f, 0.f, 0.f};
    }
    int slotk[4];
    {
        const int sw = r & 7;
        #pragma unroll
        for (int kk = 0; kk < 4; ++kk) slotk[kk] = ((kk * 4 + q) ^ sw) * 4;
    }
    #pragma unroll
    for (int mt = 0; mt < 4; ++mt) {
        const unsigned* p1 = sA1 + (mt * 16 + r) * 64;
        const unsigned* p2 = sA2 + (mt * 16 + r) * 64;
        #pragma unroll
        for (int kk = 0; kk < 4; ++kk) {
            B8 a1, a2;
            a1.q = *(const uint4*)(p1 + slotk[kk]);
            a2.q = *(const uint4*)(p2 + slotk[kk]);
            acc[mt][0] = __builtin_amdgcn_mfma_f32_16x16x32_bf16(a1.v, Wf[0][0][kk], acc[mt][0], 0, 0, 0);
            acc[mt][0] = __builtin_amdgcn_mfma_f32_16x16x32_bf16(a2.v, Wf[1][0][kk], acc[mt][0], 0, 0, 0);
            acc[mt][1] = __builtin_amdgcn_mfma_f32_16x16x32_bf16(a1.v, Wf[0][1][kk], acc[mt][1], 0, 0, 0);
            acc[mt][1] = __builtin_amdgcn_mfma_f32_16x16x32_bf16(a2.v, Wf[1][1][kk], acc[mt][1], 0, 0, 0);
        }
    }

    // ---- bias + leaky_relu; per-node partial square-sums (this wave's 32 cols)
    // C/D layout: col = lane&15, row = q*4 + reg  -> node = base+mt*16+q*4+i
    #pragma unroll
    for (int mt = 0; mt < 4; ++mt) {
        #pragma unroll
        for (int i = 0; i < 4; ++i) {
            float y0 = acc[mt][0][i] + bias0; y0 = (y0 >= 0.f) ? y0 : 0.01f * y0;
            float y1 = acc[mt][1][i] + bias1; y1 = (y1 >= 0.f) ? y1 : 0.01f * y1;
            acc[mt][0][i] = y0; acc[mt][1][i] = y1;
            float s = y0 * y0 + y1 * y1;
            s += __shfl_xor(s, 1); s += __shfl_xor(s, 2);
            s += __shfl_xor(s, 4); s += __shfl_xor(s, 8);   // reduce 16 lanes (same q)
            if (r == 0) sPart[wave * 64 + mt * 16 + q * 4 + i] = s;
        }
    }
    __syncthreads();

    // ---- total norm, scale, store
    #pragma unroll
    for (int mt = 0; mt < 4; ++mt) {
        #pragma unroll
        for (int i = 0; i < 4; ++i) {
            int nl = mt * 16 + q * 4 + i;
            float tot = sPart[nl] + sPart[64 + nl] + sPart[128 + nl] + sPart[192 + nl];
            float inv = 1.0f / fmaxf(sqrtf(tot), 1e-12f);
            int node = base + nl;
            if (node < N_NODES) {
                float y0 = acc[mt][0][i] * inv;
                float y1 = acc[mt][1][i] * inv;
                out[(size_t)node * 384 + outoff + colbase + r]      = y0;
                out[(size_t)node * 384 + outoff + colbase + 16 + r] = y1;
                if (write_x) {
                    ((unsigned short*)xbuf)[(size_t)node * 128 + colbase + r]      = f2bs(y0);
                    ((unsigned short*)xbuf)[(size_t)node * 128 + colbase + 16 + r] = f2bs(y1);
                }
            }
        }
    }
}

// ---------------------------------------------------------------------------
extern "C" void kernel_launch(void* const* d_in, const int* in_sizes, int n_in,
                              void* d_out, int out_size, void* d_ws, size_t ws_size,
                              hipStream_t stream)
{
    const int*   adj_row  = (const int*)d_in[0];
    const int*   adj_col  = (const int*)d_in[1];
    const float* adj_vals = (const float*)d_in[2];
    const float* emb      = (const float*)d_in[3];
    const float* W1_w     = (const float*)d_in[4];
    const float* W1_b     = (const float*)d_in[5];
    const float* W2_w     = (const float*)d_in[6];
    const float* W2_b     = (const float*)d_in[7];
    float* out = (float*)d_out;

    // ---- workspace layout (bytes; all 16B-aligned). Total ~64.95 MB.
    uint8_t* w = (uint8_t*)d_ws;
    unsigned* xbuf    = (unsigned*)(w);                 // NPAD*128 bf16 = 25,608,192 B
    unsigned* sideb   = (unsigned*)(w + 25608192);      // NPAD*128 bf16
    int2*     edges   = (int2*)    (w + 51216384);      // NNZ*8 = 12,800,000 B
    unsigned* w1b     = (unsigned*)(w + 64016384);      // 2*128*128 bf16 = 65,536 B
    unsigned* w2b     = (unsigned*)(w + 64081920);      // 65,536 B
    int*      row_ptr = (int*)     (w + 64147456);      // (N+1)*4
    int*      cnt     = (int*)     (w + 64547472);      // N*4 (hist counts, then countdown)
    int*      tsums   = (int*)     (w + 64947488);      // N_TILES*4

    prep_kernel<<<128, 256, 0, stream>>>(W1_w, W2_w, w1b, w2b, cnt);
    copy_emb_kernel<<<NPAD * 32 / 256, 256, 0, stream>>>(emb, out, xbuf);

    // ---- CSR build (no memsets: prep zeroed cnt; scatter counts it back down)
    hist_kernel<<<NNZ_E / 256, 256, 0, stream>>>(adj_row, cnt);
    scan_pass_a<<<N_TILES, 256, 0, stream>>>(cnt, tsums);
    scan_pass_b<<<1, 64, 0, stream>>>(tsums);
    scan_pass_c<<<N_TILES, 256, 0, stream>>>(cnt, tsums, row_ptr);
    scatter_kernel<<<NNZ_E / 256, 256, 0, stream>>>(
        adj_row, adj_col, adj_vals, row_ptr, cnt, edges);

    for (int k = 0; k < 2; ++k) {
        spmm_gather_bf16<<<NPAD / 8, 256, 0, stream>>>(
            row_ptr, edges, (const uint2*)xbuf, (uint2*)sideb);
        dense_mfma_kernel<<<NPAD / 64, 256, 0, stream>>>(
            sideb, xbuf, w1b + k * 8192, w2b + k * 8192,
            W1_b + k * DIM, W2_b + k * DIM,
            out, DIM * (k + 1), (k == 0) ? 1 : 0);
    }
}